// Round 4
// baseline (2623.347 us; speedup 1.0000x reference)
//
#include <hip/hip_runtime.h>
#include <hip/hip_bf16.h>

#define BATCH 1024
#define HID   512
#define OUTW  348   // 12 * (8+6+4+11)

using short8 = __attribute__((ext_vector_type(8))) short;
using bf16x8 = __attribute__((ext_vector_type(8))) __bf16;
using f32x4  = __attribute__((ext_vector_type(4))) float;

__device__ __forceinline__ float bf2f(unsigned short u) {
  union { unsigned int i; float f; } x; x.i = ((unsigned int)u) << 16; return x.f;
}
__device__ __forceinline__ unsigned short f2bf(float f) {
  __hip_bfloat16 b = __float2bfloat16(f);
  return __builtin_bit_cast(unsigned short, b);
}
__device__ __forceinline__ float sigm(float x) { return 1.0f / (1.0f + __expf(-x)); }

__device__ __forceinline__ f32x4 mfma_bf16(short8 a, short8 b, f32x4 c) {
  return __builtin_amdgcn_mfma_f32_16x16x32_bf16(
      __builtin_bit_cast(bf16x8, a), __builtin_bit_cast(bf16x8, b), c, 0, 0, 0);
}

typedef const __attribute__((address_space(1))) unsigned int* gas_p;
typedef __attribute__((address_space(3))) unsigned int* las_p;
__device__ __forceinline__ void gload16(const void* g, void* l) {
  __builtin_amdgcn_global_load_lds((gas_p)g, (las_p)l, 16, 0, 0);
}

// ---------------- setup kernels ----------------

__global__ void k_convert(const float* __restrict__ src, unsigned short* __restrict__ dst, int n) {
  int i = (blockIdx.x * blockDim.x + threadIdx.x) * 4;
  if (i + 3 < n) {
    float4 v = *(const float4*)(src + i);
    dst[i + 0] = f2bf(v.x); dst[i + 1] = f2bf(v.y);
    dst[i + 2] = f2bf(v.z); dst[i + 3] = f2bf(v.w);
  } else {
    for (int j = 0; j < 4 && i + j < n; ++j) dst[i + j] = f2bf(src[i + j]);
  }
}

// Wqp[128][512] bf16: rows 0..63 = Wcurr, 64..127 = Wprev
__global__ void k_wqp(const float* __restrict__ Wcurr, const float* __restrict__ Wprev,
                      unsigned short* __restrict__ dst) {
  int i = blockIdx.x * blockDim.x + threadIdx.x;  // < 128*512
  int row = i >> 9, col = i & 511;
  float v = (row < 64) ? Wcurr[row * 512 + col] : Wprev[(row - 64) * 512 + col];
  dst[i] = f2bf(v);
}

__global__ void k_bias(const float* __restrict__ bih, const float* __restrict__ bhh,
                       float* __restrict__ bsum) {
  int i = blockIdx.x * blockDim.x + threadIdx.x;
  if (i < 4096) bsum[i] = bih[i] + bhh[i];
}

__global__ void k_zero(uint4* __restrict__ p, int n16) {
  int i = blockIdx.x * blockDim.x + threadIdx.x;
  if (i < n16) p[i] = make_uint4(0u, 0u, 0u, 0u);
}

// P[0][r][a] = bprev[a]
__global__ void k_p0(float* __restrict__ P, const float* __restrict__ bprev) {
  int i = blockIdx.x * blockDim.x + threadIdx.x;  // < 1024*64
  P[i] = bprev[i & 63];
}

// ---------------- fused gates dispatch ----------------
// Up to two independent LSTM layer-GEMMs (128 blocks each) + optional classifier (32 blocks).
// GEMM tile: 128 batch x 32 cells (=128 gate rows), BK=64, K=1024 (X||H).
// Block: 256 thr (4 waves). Wave (wm,wc): 64 batch x 16 cells x 4 gates, acc[4][4].

struct GJob {
  const unsigned short *X, *H, *Wih, *Whh;
  const float *bias;
  float *C;
  unsigned short *Hout;
};
struct CJob {
  const unsigned short* h;
  const float *Wc, *bc;
  float* out;
  int obase;
};

__device__ __forceinline__ void run_gemm(const GJob& j, int lb,
                                         unsigned short (*Ab)[8192],
                                         unsigned short (*Bb)[8192]) {
  const int tid = threadIdx.x, w = tid >> 6, lane = tid & 63;
  const int wm = w & 1, wc = w >> 1;
  const int mt = lb & 7, nt = lb >> 3;
  const int m0 = mt * 128, n0 = nt * 32;
  const int l16 = lane & 15, kg = lane >> 4;

  auto stage = [&](int kt, int buf) {
    const unsigned short* As = (kt < 8) ? j.X : j.H;
    const unsigned short* Bs = (kt < 8) ? j.Wih : j.Whh;
    const int k0 = (kt & 7) * 64;
#pragma unroll
    for (int i = 0; i < 4; ++i) {
      int g = i * 256 + tid;
      int row = g >> 3, cg = g & 7;
      int ke = (cg ^ (row & 7)) << 3;
      gload16(As + (size_t)(m0 + row) * HID + k0 + ke, &Ab[buf][g * 8]);
    }
#pragma unroll
    for (int i = 0; i < 4; ++i) {
      int g = i * 256 + tid;
      int fr = g >> 3, cg = g & 7;
      int gate = fr >> 5, cell = fr & 31;
      int ke = (cg ^ (fr & 7)) << 3;
      gload16(Bs + (size_t)(gate * HID + n0 + cell) * HID + k0 + ke, &Bb[buf][g * 8]);
    }
  };

  f32x4 acc[4][4];  // [mi][gate]
#pragma unroll
  for (int mi = 0; mi < 4; ++mi)
#pragma unroll
    for (int g = 0; g < 4; ++g) acc[mi][g] = (f32x4)(0.0f);

  stage(0, 0);
  for (int kt = 0; kt < 16; ++kt) {
    __syncthreads();
    if (kt < 15) stage(kt + 1, (kt + 1) & 1);
    const int buf = kt & 1;
#pragma unroll
    for (int ko = 0; ko < 2; ++ko) {
      const int acb = ko * 64 + kg * 16;
      short8 a[4], b[4];
#pragma unroll
      for (int mi = 0; mi < 4; ++mi) {
        const int r = wm * 64 + mi * 16 + l16;
        a[mi] = *(const short8*)&Ab[buf][r * 64 + ((acb ^ ((r & 7) << 4)) >> 1)];
      }
#pragma unroll
      for (int g = 0; g < 4; ++g) {
        const int fr = g * 32 + wc * 16 + l16;
        b[g] = *(const short8*)&Bb[buf][fr * 64 + ((acb ^ ((fr & 7) << 4)) >> 1)];
      }
#pragma unroll
      for (int mi = 0; mi < 4; ++mi)
#pragma unroll
        for (int g = 0; g < 4; ++g) acc[mi][g] = mfma_bf16(a[mi], b[g], acc[mi][g]);
    }
  }

  const int cell = n0 + wc * 16 + l16;
  const float b0 = j.bias[cell], b1 = j.bias[512 + cell];
  const float b2 = j.bias[1024 + cell], b3 = j.bias[1536 + cell];
#pragma unroll
  for (int mi = 0; mi < 4; ++mi) {
#pragma unroll
    for (int r = 0; r < 4; ++r) {
      const int m = m0 + wm * 64 + mi * 16 + kg * 4 + r;
      float gi = acc[mi][0][r] + b0;
      float gf = acc[mi][1][r] + b1;
      float gg = acc[mi][2][r] + b2;
      float go = acc[mi][3][r] + b3;
      float cold = j.C[m * HID + cell];
      float cn = sigm(gf) * cold + sigm(gi) * tanhf(gg);
      float hn = sigm(go) * tanhf(cn);
      j.C[m * HID + cell] = cn;
      j.Hout[m * HID + cell] = f2bf(hn);
    }
  }
}

template <int S>
__device__ __forceinline__ void run_cls(const CJob& c, int cb) {
  const int w = threadIdx.x >> 6, lane = threadIdx.x & 63;
#pragma unroll
  for (int i = 0; i < 8; ++i) {
    const int r = (cb * 4 + w) * 8 + i;
    short8 hv = *(const short8*)(c.h + r * HID + lane * 8);
    float hf[8];
#pragma unroll
    for (int j = 0; j < 8; ++j) hf[j] = bf2f((unsigned short)hv[j]);
    float logit[S];
#pragma unroll
    for (int s = 0; s < S; ++s) {
      const float* wr = c.Wc + s * HID + lane * 8;
      float p = 0.f;
#pragma unroll
      for (int j = 0; j < 8; ++j) p += hf[j] * wr[j];
#pragma unroll
      for (int off = 32; off; off >>= 1) p += __shfl_xor(p, off);
      logit[s] = p + c.bc[s];
    }
    if (lane == 0) {
      float m = logit[0];
#pragma unroll
      for (int s = 1; s < S; ++s) m = fmaxf(m, logit[s]);
      float e[S], den = 0.f;
#pragma unroll
      for (int s = 0; s < S; ++s) { e[s] = __expf(logit[s] - m); den += e[s]; }
      float inv = 1.0f / den;
#pragma unroll
      for (int s = 0; s < S; ++s) c.out[r * OUTW + c.obase + s] = e[s] * inv;
    }
  }
}

template <int S, bool HASB>
__global__ __launch_bounds__(256, 2) void k_gates2(GJob A, GJob B, CJob C) {
  __shared__ unsigned short Ab[2][8192];
  __shared__ unsigned short Bb[2][8192];
  const int b = blockIdx.x;
  if (b < 128) {
    run_gemm(A, b, Ab, Bb);
  } else if (HASB && b < 256) {
    run_gemm(B, b - 128, Ab, Bb);
  } else {
    if constexpr (S > 0) run_cls<S>(C, b - (HASB ? 256 : 128));
  }
}

// ---------------- anchor projections: [Q || Pnew] = h1 @ Wqp^T ----------------
__global__ __launch_bounds__(256) void k_qp(
    const unsigned short* __restrict__ h1,
    const unsigned short* __restrict__ Wqp,   // [128][512] bf16
    const float* __restrict__ bcurr, const float* __restrict__ bprev,
    float* __restrict__ Q,                    // [1024][64]
    float* __restrict__ P,                    // [12][1024][64]
    int cyc) {
  __shared__ unsigned short Ab[2][4096];
  __shared__ unsigned short Bb[2][1024];
  const int w = threadIdx.x >> 6, lane = threadIdx.x & 63;
  const int m0 = blockIdx.x * 64, n0 = blockIdx.y * 16;
  const int l16 = lane & 15, kg = lane >> 4;

  auto stage = [&](int kt, int buf) {
    const int k0 = kt * 64;
#pragma unroll
    for (int j = 0; j < 2; ++j) {
      int s = w * 128 + j * 64 + lane;
      int row = s >> 3;
      int ke = ((s & 7) ^ (row & 7)) << 3;
      gload16(h1 + (size_t)(m0 + row) * HID + k0 + ke, &Ab[buf][(w * 128 + j * 64) * 8]);
    }
    if (w < 2) {
      int s = w * 64 + lane;
      int row = s >> 3;
      int ke = ((s & 7) ^ (row & 7)) << 3;
      gload16(Wqp + (size_t)(n0 + row) * HID + k0 + ke, &Bb[buf][(w * 64) * 8]);
    }
  };

  f32x4 acc = (f32x4)(0.0f);
  stage(0, 0);
  for (int kt = 0; kt < 8; ++kt) {
    __syncthreads();
    if (kt < 7) stage(kt + 1, (kt + 1) & 1);
    const int buf = kt & 1;
#pragma unroll
    for (int ko = 0; ko < 2; ++ko) {
      const int acb = ko * 64 + kg * 16;
      const int ar = w * 16 + l16;
      short8 a = *(const short8*)&Ab[buf][ar * 64 + ((acb ^ ((ar & 7) << 4)) >> 1)];
      const int br = l16;
      short8 b = *(const short8*)&Bb[buf][br * 64 + ((acb ^ ((br & 7) << 4)) >> 1)];
      acc = mfma_bf16(a, b, acc);
    }
  }

  const int col = n0 + l16;
  const int r0 = m0 + w * 16 + kg * 4;
#pragma unroll
  for (int r = 0; r < 4; ++r) {
    const int m = r0 + r;
    float val = acc[r] + (col < 64 ? bcurr[col] : bprev[col - 64]);
    if (col < 64) Q[m * 64 + col] = val;
    else if (cyc + 1 < 12) P[(cyc + 1) * (BATCH * 64) + m * 64 + (col - 64)] = val;
  }
}

// ---------------- anchor scores + embedding ----------------
template <int CYC>
__global__ __launch_bounds__(256) void k_scores(
    const float* __restrict__ Q, const float* __restrict__ P,
    const float* __restrict__ vv, const float* __restrict__ Wanc,
    const float* __restrict__ banc, float* __restrict__ out,
    unsigned short* __restrict__ X) {
  const int w = threadIdx.x >> 6, lane = threadIdx.x & 63;
  const int r = blockIdx.x * 4 + w;
  const float q = Q[r * 64 + lane];
  const float vl = vv[lane];
  float sk[CYC > 0 ? CYC : 1];
#pragma unroll
  for (int k = 0; k < CYC; ++k) {
    float t = tanhf(P[k * (BATCH * 64) + r * 64 + lane] + q) * vl;
#pragma unroll
    for (int off = 32; off; off >>= 1) t += __shfl_xor(t, off);
    sk[k] = sigm(t);
  }
  float ov = 0.0f;
#pragma unroll
  for (int k = 0; k < 11; ++k)
    if (lane == k) ov = (k < CYC) ? sk[k] : 0.0f;
  if (lane < 11) out[r * OUTW + CYC * 29 + 18 + lane] = ov;

  const int d0 = lane * 8;
#pragma unroll
  for (int j = 0; j < 8; ++j) {
    const int d = d0 + j;
    float x = banc[d];
#pragma unroll
    for (int k = 0; k < CYC; ++k) x += sk[k] * Wanc[d * 11 + k];
    X[r * HID + d] = f2bf(x);
  }
}

// ---------------- launcher ----------------

extern "C" void kernel_launch(void* const* d_in, const int* in_sizes, int n_in,
                              void* d_out, int out_size, void* d_ws, size_t ws_size,
                              hipStream_t stream) {
  const float* x0    = (const float*)d_in[0];
  const float* lWih  = (const float*)d_in[1];
  const float* lWhh  = (const float*)d_in[2];
  const float* lbih  = (const float*)d_in[3];
  const float* lbhh  = (const float*)d_in[4];
  const float* Wc0   = (const float*)d_in[5];
  const float* bc0   = (const float*)d_in[6];
  const float* Wc1   = (const float*)d_in[7];
  const float* bc1   = (const float*)d_in[8];
  const float* Wc2   = (const float*)d_in[9];
  const float* bc2   = (const float*)d_in[10];
  const float* Wprev = (const float*)d_in[11];
  const float* bprev = (const float*)d_in[12];
  const float* Wcurr = (const float*)d_in[13];
  const float* bcurr = (const float*)d_in[14];
  const float* Wanc  = (const float*)d_in[15];
  const float* banc  = (const float*)d_in[16];
  const float* v     = (const float*)d_in[17];
  float* out = (float*)d_out;

  const size_t NW  = 2 * 2048 * 512;
  const size_t NBH = (size_t)BATCH * HID;

  char* ws = (char*)d_ws;
  size_t off = 0;
  auto alloc = [&](size_t bytes) { char* p = ws + off; off += (bytes + 255) & ~(size_t)255; return p; };
  unsigned short* Wih_b = (unsigned short*)alloc(NW * 2);
  unsigned short* Whh_b = (unsigned short*)alloc(NW * 2);
  unsigned short* Wqp_b = (unsigned short*)alloc(128 * 512 * 2);
  float*          biasS = (float*)alloc(4096 * 4);
  unsigned short* Xb    = (unsigned short*)alloc(NBH * 2);
  unsigned short* Hb0   = (unsigned short*)alloc(2 * NBH * 2);
  unsigned short* Hb1   = (unsigned short*)alloc(2 * NBH * 2);
  float*          C0    = (float*)alloc(NBH * 4);
  float*          C1    = (float*)alloc(NBH * 4);
  float*          P     = (float*)alloc((size_t)12 * BATCH * 64 * 4);
  float*          Qb    = (float*)alloc((size_t)BATCH * 64 * 4);

  k_convert<<<dim3((NW / 4 + 255) / 256), dim3(256), 0, stream>>>(lWih, Wih_b, (int)NW);
  k_convert<<<dim3((NW / 4 + 255) / 256), dim3(256), 0, stream>>>(lWhh, Whh_b, (int)NW);
  k_convert<<<dim3((NBH / 4 + 255) / 256), dim3(256), 0, stream>>>(x0, Xb, (int)NBH);
  k_wqp<<<dim3(256), dim3(256), 0, stream>>>(Wcurr, Wprev, Wqp_b);
  k_bias<<<dim3(16), dim3(256), 0, stream>>>(lbih, lbhh, biasS);
  {
    size_t zb = 2 * NBH * 2 + 2 * NBH * 2 + NBH * 4 + NBH * 4;  // Hb0,Hb1,C0,C1 contiguous
    int n16 = (int)(zb / 16);
    k_zero<<<dim3((n16 + 255) / 256), dim3(256), 0, stream>>>((uint4*)Hb0, n16);
  }
  k_p0<<<dim3(256), dim3(256), 0, stream>>>(P, bprev);

  // job builders (buffer parity: writer of step t uses parity (t+1)&1)
  auto jobL0 = [&](int u) {
    GJob j; j.X = Xb; j.H = Hb0 + (u & 1) * NBH;
    j.Wih = Wih_b; j.Whh = Whh_b; j.bias = biasS; j.C = C0;
    j.Hout = Hb0 + ((u + 1) & 1) * NBH; return j;
  };
  auto jobL1 = [&](int t) {
    GJob j; j.X = Hb0 + ((t + 1) & 1) * NBH; j.H = Hb1 + (t & 1) * NBH;
    j.Wih = Wih_b + 2048 * 512; j.Whh = Whh_b + 2048 * 512; j.bias = biasS + 2048; j.C = C1;
    j.Hout = Hb1 + ((t + 1) & 1) * NBH; return j;
  };
  auto h1of = [&](int t) { return (const unsigned short*)(Hb1 + ((t + 1) & 1) * NBH); };
  GJob dummy{}; CJob nocls{};

  // prologue: L0(step 0)
  k_gates2<0, false><<<dim3(128), dim3(256), 0, stream>>>(jobL0(0), dummy, nocls);

  for (int c = 0; c < 12; ++c) {
    const int t0 = 4 * c, t1 = t0 + 1, t2 = t0 + 2, t3 = t0 + 3;
    const int base = c * 29;
    CJob cls0{h1of(t0), Wc0, bc0, out, base};
    CJob cls1{h1of(t1), Wc1, bc1, out, base + 8};
    CJob cls2{h1of(t2), Wc2, bc2, out, base + 14};

    k_gates2<0, true><<<dim3(256), dim3(256), 0, stream>>>(jobL1(t0), jobL0(t1), nocls);
    k_gates2<8, true><<<dim3(288), dim3(256), 0, stream>>>(jobL1(t1), jobL0(t2), cls0);
    k_gates2<6, true><<<dim3(288), dim3(256), 0, stream>>>(jobL1(t2), jobL0(t3), cls1);
    k_gates2<4, false><<<dim3(160), dim3(256), 0, stream>>>(jobL1(t3), dummy, cls2);

    k_qp<<<dim3(16, 8), dim3(256), 0, stream>>>(h1of(t3), Wqp_b, bcurr, bprev, Qb, P, c);
    switch (c) {
      case 0:  k_scores<0><<<dim3(256), dim3(256), 0, stream>>>(Qb, P, v, Wanc, banc, out, Xb); break;
      case 1:  k_scores<1><<<dim3(256), dim3(256), 0, stream>>>(Qb, P, v, Wanc, banc, out, Xb); break;
      case 2:  k_scores<2><<<dim3(256), dim3(256), 0, stream>>>(Qb, P, v, Wanc, banc, out, Xb); break;
      case 3:  k_scores<3><<<dim3(256), dim3(256), 0, stream>>>(Qb, P, v, Wanc, banc, out, Xb); break;
      case 4:  k_scores<4><<<dim3(256), dim3(256), 0, stream>>>(Qb, P, v, Wanc, banc, out, Xb); break;
      case 5:  k_scores<5><<<dim3(256), dim3(256), 0, stream>>>(Qb, P, v, Wanc, banc, out, Xb); break;
      case 6:  k_scores<6><<<dim3(256), dim3(256), 0, stream>>>(Qb, P, v, Wanc, banc, out, Xb); break;
      case 7:  k_scores<7><<<dim3(256), dim3(256), 0, stream>>>(Qb, P, v, Wanc, banc, out, Xb); break;
      case 8:  k_scores<8><<<dim3(256), dim3(256), 0, stream>>>(Qb, P, v, Wanc, banc, out, Xb); break;
      case 9:  k_scores<9><<<dim3(256), dim3(256), 0, stream>>>(Qb, P, v, Wanc, banc, out, Xb); break;
      case 10: k_scores<10><<<dim3(256), dim3(256), 0, stream>>>(Qb, P, v, Wanc, banc, out, Xb); break;
      default: k_scores<11><<<dim3(256), dim3(256), 0, stream>>>(Qb, P, v, Wanc, banc, out, Xb); break;
    }
    if (c < 11)
      k_gates2<0, false><<<dim3(128), dim3(256), 0, stream>>>(jobL0(t3 + 1), dummy, nocls);
  }
  (void)in_sizes; (void)n_in; (void)out_size; (void)ws_size;
}

// Round 5
// 1947.960 us; speedup vs baseline: 1.3467x; 1.3467x over previous
//
#include <hip/hip_runtime.h>
#include <hip/hip_bf16.h>

#define BATCH 1024
#define HID   512
#define OUTW  348   // 12 * (8+6+4+11)

using short8 = __attribute__((ext_vector_type(8))) short;
using bf16x8 = __attribute__((ext_vector_type(8))) __bf16;
using f32x4  = __attribute__((ext_vector_type(4))) float;

__device__ __forceinline__ float bf2f(unsigned short u) {
  union { unsigned int i; float f; } x; x.i = ((unsigned int)u) << 16; return x.f;
}
__device__ __forceinline__ unsigned short f2bf(float f) {
  __hip_bfloat16 b = __float2bfloat16(f);
  return __builtin_bit_cast(unsigned short, b);
}
__device__ __forceinline__ float sigm(float x) { return 1.0f / (1.0f + __expf(-x)); }

__device__ __forceinline__ f32x4 mfma_bf16(short8 a, short8 b, f32x4 c) {
  return __builtin_amdgcn_mfma_f32_16x16x32_bf16(
      __builtin_bit_cast(bf16x8, a), __builtin_bit_cast(bf16x8, b), c, 0, 0, 0);
}

typedef const __attribute__((address_space(1))) unsigned int* gas_p;
typedef __attribute__((address_space(3))) unsigned int* las_p;
__device__ __forceinline__ void gload16(const void* g, void* l) {
  __builtin_amdgcn_global_load_lds((gas_p)g, (las_p)l, 16, 0, 0);
}

// ---------------- setup kernels ----------------

__global__ void k_convert(const float* __restrict__ src, unsigned short* __restrict__ dst, int n) {
  int i = (blockIdx.x * blockDim.x + threadIdx.x) * 4;
  if (i + 3 < n) {
    float4 v = *(const float4*)(src + i);
    dst[i + 0] = f2bf(v.x); dst[i + 1] = f2bf(v.y);
    dst[i + 2] = f2bf(v.z); dst[i + 3] = f2bf(v.w);
  } else {
    for (int j = 0; j < 4 && i + j < n; ++j) dst[i + j] = f2bf(src[i + j]);
  }
}

// Wqp[128][512] bf16: rows 0..63 = Wcurr, 64..127 = Wprev
__global__ void k_wqp(const float* __restrict__ Wcurr, const float* __restrict__ Wprev,
                      unsigned short* __restrict__ dst) {
  int i = blockIdx.x * blockDim.x + threadIdx.x;  // < 128*512
  int row = i >> 9, col = i & 511;
  float v = (row < 64) ? Wcurr[row * 512 + col] : Wprev[(row - 64) * 512 + col];
  dst[i] = f2bf(v);
}

__global__ void k_bias(const float* __restrict__ bih, const float* __restrict__ bhh,
                       float* __restrict__ bsum) {
  int i = blockIdx.x * blockDim.x + threadIdx.x;
  if (i < 4096) bsum[i] = bih[i] + bhh[i];
}

__global__ void k_zero(uint4* __restrict__ p, int n16) {
  int i = blockIdx.x * blockDim.x + threadIdx.x;
  if (i < n16) p[i] = make_uint4(0u, 0u, 0u, 0u);
}

// P[0][r][a] = bprev[a]
__global__ void k_p0(float* __restrict__ P, const float* __restrict__ bprev) {
  int i = blockIdx.x * blockDim.x + threadIdx.x;  // < 1024*64
  P[i] = bprev[i & 63];
}

// ---------------- fused gates dispatch (round-2 tile + XCD-affine swizzle) ----------------
// GEMM tile: BM=64 batch x 16 cells (=64 gate rows), BK=64, K=1024 (X||H).
// 512 blocks per layer-job; lb -> (mt, nt) swizzled so XCD = lb%8 owns a fixed
// 64-cell slice (weights 262 KB/layer/XCD stay L2-hot across all 48 steps).
// Block: 256 thr (4 waves). Wave w: rows w*16..w*16+15, all 16 cells x 4 gates.

struct GJob {
  const unsigned short *X, *H, *Wih, *Whh;
  const float *bias;
  float *C;
  unsigned short *Hout;
};
struct CJob {
  const unsigned short* h;
  const float *Wc, *bc;
  float* out;
  int obase;
};

__device__ __forceinline__ void run_gemm(const GJob& j, int lb,
                                         unsigned short (*Ab)[4096],
                                         unsigned short (*Bb)[4096]) {
  const int w = threadIdx.x >> 6, lane = threadIdx.x & 63;
  // XCD-affine: nt = (lb&7)*4 + ((lb>>3)&3), mt = lb>>5  (bijective on [0,512))
  const int mt = lb >> 5;
  const int nt = (lb & 7) * 4 + ((lb >> 3) & 3);
  const int m0 = mt * 64;
  const int n0 = nt * 16;
  const int l16 = lane & 15, kg = lane >> 4;

  auto stage = [&](int kt, int buf) {
    const unsigned short* Asrc = (kt < 8) ? j.X : j.H;
    const unsigned short* Wsrc = (kt < 8) ? j.Wih : j.Whh;
    const int k0 = (kt & 7) * 64;
#pragma unroll
    for (int i = 0; i < 2; ++i) {
      int s = w * 128 + i * 64 + lane;
      int row = s >> 3;
      int ke = ((s & 7) ^ (row & 7)) << 3;  // swizzled source element offset
      gload16(Asrc + (size_t)(m0 + row) * HID + k0 + ke, &Ab[buf][(w * 128 + i * 64) * 8]);
    }
#pragma unroll
    for (int i = 0; i < 2; ++i) {
      int s = w * 128 + i * 64 + lane;
      int fr = s >> 3;                       // 0..63 = g*16+c
      int g = fr >> 4, c = fr & 15;
      int ke = ((s & 7) ^ (fr & 7)) << 3;
      gload16(Wsrc + (size_t)(g * 512 + n0 + c) * HID + k0 + ke, &Bb[buf][(w * 128 + i * 64) * 8]);
    }
  };

  f32x4 acc[4];
#pragma unroll
  for (int g = 0; g < 4; ++g) acc[g] = (f32x4)(0.0f);

  stage(0, 0);
  for (int kt = 0; kt < 16; ++kt) {
    __syncthreads();
    if (kt < 15) stage(kt + 1, (kt + 1) & 1);
    const int buf = kt & 1;
#pragma unroll
    for (int ko = 0; ko < 2; ++ko) {
      const int acb = ko * 64 + kg * 16;       // logical col byte within 128B row
      const int ar = w * 16 + l16;
      short8 a = *(const short8*)&Ab[buf][ar * 64 + ((acb ^ ((ar & 7) << 4)) >> 1)];
#pragma unroll
      for (int g = 0; g < 4; ++g) {
        const int br = g * 16 + l16;
        short8 b = *(const short8*)&Bb[buf][br * 64 + ((acb ^ ((br & 7) << 4)) >> 1)];
        acc[g] = mfma_bf16(a, b, acc[g]);
      }
    }
  }

  const int ccol = n0 + l16;
  const int crow = m0 + w * 16 + kg * 4;
  const float b0 = j.bias[ccol], b1 = j.bias[512 + ccol];
  const float b2 = j.bias[1024 + ccol], b3 = j.bias[1536 + ccol];
#pragma unroll
  for (int r = 0; r < 4; ++r) {
    const int m = crow + r;
    float gi = acc[0][r] + b0;
    float gf = acc[1][r] + b1;
    float gg = acc[2][r] + b2;
    float go = acc[3][r] + b3;
    float cold = j.C[m * HID + ccol];
    float cn = sigm(gf) * cold + sigm(gi) * tanhf(gg);
    float hn = sigm(go) * tanhf(cn);
    j.C[m * HID + ccol] = cn;
    j.Hout[m * HID + ccol] = f2bf(hn);
  }
}

template <int S>
__device__ __forceinline__ void run_cls(const CJob& c, int cb) {
  const int w = threadIdx.x >> 6, lane = threadIdx.x & 63;
#pragma unroll
  for (int i = 0; i < 8; ++i) {
    const int r = (cb * 4 + w) * 8 + i;
    short8 hv = *(const short8*)(c.h + r * HID + lane * 8);
    float hf[8];
#pragma unroll
    for (int j = 0; j < 8; ++j) hf[j] = bf2f((unsigned short)hv[j]);
    float logit[S];
#pragma unroll
    for (int s = 0; s < S; ++s) {
      const float* wr = c.Wc + s * HID + lane * 8;
      float p = 0.f;
#pragma unroll
      for (int j = 0; j < 8; ++j) p += hf[j] * wr[j];
#pragma unroll
      for (int off = 32; off; off >>= 1) p += __shfl_xor(p, off);
      logit[s] = p + c.bc[s];
    }
    if (lane == 0) {
      float m = logit[0];
#pragma unroll
      for (int s = 1; s < S; ++s) m = fmaxf(m, logit[s]);
      float e[S], den = 0.f;
#pragma unroll
      for (int s = 0; s < S; ++s) { e[s] = __expf(logit[s] - m); den += e[s]; }
      float inv = 1.0f / den;
#pragma unroll
      for (int s = 0; s < S; ++s) c.out[r * OUTW + c.obase + s] = e[s] * inv;
    }
  }
}

template <int S, bool HASB>
__global__ __launch_bounds__(256, 4) void k_gates2(GJob A, GJob B, CJob C) {
  __shared__ unsigned short Ab[2][4096];
  __shared__ unsigned short Bb[2][4096];
  const int b = blockIdx.x;
  if (b < 512) {
    run_gemm(A, b, Ab, Bb);
  } else if (HASB && b < 1024) {
    run_gemm(B, b - 512, Ab, Bb);
  } else {
    if constexpr (S > 0) run_cls<S>(C, b - (HASB ? 1024 : 512));
  }
}

// ---------------- anchor projections: [Q || Pnew] = h1 @ Wqp^T ----------------
__global__ __launch_bounds__(256) void k_qp(
    const unsigned short* __restrict__ h1,
    const unsigned short* __restrict__ Wqp,   // [128][512] bf16
    const float* __restrict__ bcurr, const float* __restrict__ bprev,
    float* __restrict__ Q,                    // [1024][64]
    float* __restrict__ P,                    // [12][1024][64]
    int cyc) {
  __shared__ unsigned short Ab[2][4096];
  __shared__ unsigned short Bb[2][1024];
  const int w = threadIdx.x >> 6, lane = threadIdx.x & 63;
  const int m0 = blockIdx.x * 64, n0 = blockIdx.y * 16;
  const int l16 = lane & 15, kg = lane >> 4;

  auto stage = [&](int kt, int buf) {
    const int k0 = kt * 64;
#pragma unroll
    for (int j = 0; j < 2; ++j) {
      int s = w * 128 + j * 64 + lane;
      int row = s >> 3;
      int ke = ((s & 7) ^ (row & 7)) << 3;
      gload16(h1 + (size_t)(m0 + row) * HID + k0 + ke, &Ab[buf][(w * 128 + j * 64) * 8]);
    }
    if (w < 2) {
      int s = w * 64 + lane;
      int row = s >> 3;
      int ke = ((s & 7) ^ (row & 7)) << 3;
      gload16(Wqp + (size_t)(n0 + row) * HID + k0 + ke, &Bb[buf][(w * 64) * 8]);
    }
  };

  f32x4 acc = (f32x4)(0.0f);
  stage(0, 0);
  for (int kt = 0; kt < 8; ++kt) {
    __syncthreads();
    if (kt < 7) stage(kt + 1, (kt + 1) & 1);
    const int buf = kt & 1;
#pragma unroll
    for (int ko = 0; ko < 2; ++ko) {
      const int acb = ko * 64 + kg * 16;
      const int ar = w * 16 + l16;
      short8 a = *(const short8*)&Ab[buf][ar * 64 + ((acb ^ ((ar & 7) << 4)) >> 1)];
      const int br = l16;
      short8 b = *(const short8*)&Bb[buf][br * 64 + ((acb ^ ((br & 7) << 4)) >> 1)];
      acc = mfma_bf16(a, b, acc);
    }
  }

  const int col = n0 + l16;
  const int r0 = m0 + w * 16 + kg * 4;
#pragma unroll
  for (int r = 0; r < 4; ++r) {
    const int m = r0 + r;
    float val = acc[r] + (col < 64 ? bcurr[col] : bprev[col - 64]);
    if (col < 64) Q[m * 64 + col] = val;
    else if (cyc + 1 < 12) P[(cyc + 1) * (BATCH * 64) + m * 64 + (col - 64)] = val;
  }
}

// ---------------- anchor scores + embedding ----------------
template <int CYC>
__global__ __launch_bounds__(256) void k_scores(
    const float* __restrict__ Q, const float* __restrict__ P,
    const float* __restrict__ vv, const float* __restrict__ Wanc,
    const float* __restrict__ banc, float* __restrict__ out,
    unsigned short* __restrict__ X) {
  const int w = threadIdx.x >> 6, lane = threadIdx.x & 63;
  const int r = blockIdx.x * 4 + w;
  const float q = Q[r * 64 + lane];
  const float vl = vv[lane];
  float sk[CYC > 0 ? CYC : 1];
#pragma unroll
  for (int k = 0; k < CYC; ++k) {
    float t = tanhf(P[k * (BATCH * 64) + r * 64 + lane] + q) * vl;
#pragma unroll
    for (int off = 32; off; off >>= 1) t += __shfl_xor(t, off);
    sk[k] = sigm(t);
  }
  float ov = 0.0f;
#pragma unroll
  for (int k = 0; k < 11; ++k)
    if (lane == k) ov = (k < CYC) ? sk[k] : 0.0f;
  if (lane < 11) out[r * OUTW + CYC * 29 + 18 + lane] = ov;

  const int d0 = lane * 8;
#pragma unroll
  for (int j = 0; j < 8; ++j) {
    const int d = d0 + j;
    float x = banc[d];
#pragma unroll
    for (int k = 0; k < CYC; ++k) x += sk[k] * Wanc[d * 11 + k];
    X[r * HID + d] = f2bf(x);
  }
}

// ---------------- launcher ----------------

extern "C" void kernel_launch(void* const* d_in, const int* in_sizes, int n_in,
                              void* d_out, int out_size, void* d_ws, size_t ws_size,
                              hipStream_t stream) {
  const float* x0    = (const float*)d_in[0];
  const float* lWih  = (const float*)d_in[1];
  const float* lWhh  = (const float*)d_in[2];
  const float* lbih  = (const float*)d_in[3];
  const float* lbhh  = (const float*)d_in[4];
  const float* Wc0   = (const float*)d_in[5];
  const float* bc0   = (const float*)d_in[6];
  const float* Wc1   = (const float*)d_in[7];
  const float* bc1   = (const float*)d_in[8];
  const float* Wc2   = (const float*)d_in[9];
  const float* bc2   = (const float*)d_in[10];
  const float* Wprev = (const float*)d_in[11];
  const float* bprev = (const float*)d_in[12];
  const float* Wcurr = (const float*)d_in[13];
  const float* bcurr = (const float*)d_in[14];
  const float* Wanc  = (const float*)d_in[15];
  const float* banc  = (const float*)d_in[16];
  const float* v     = (const float*)d_in[17];
  float* out = (float*)d_out;

  const size_t NW  = 2 * 2048 * 512;
  const size_t NBH = (size_t)BATCH * HID;

  char* ws = (char*)d_ws;
  size_t off = 0;
  auto alloc = [&](size_t bytes) { char* p = ws + off; off += (bytes + 255) & ~(size_t)255; return p; };
  unsigned short* Wih_b = (unsigned short*)alloc(NW * 2);
  unsigned short* Whh_b = (unsigned short*)alloc(NW * 2);
  unsigned short* Wqp_b = (unsigned short*)alloc(128 * 512 * 2);
  float*          biasS = (float*)alloc(4096 * 4);
  unsigned short* Xb    = (unsigned short*)alloc(NBH * 2);
  unsigned short* Hb0   = (unsigned short*)alloc(2 * NBH * 2);
  unsigned short* Hb1   = (unsigned short*)alloc(2 * NBH * 2);
  float*          C0    = (float*)alloc(NBH * 4);
  float*          C1    = (float*)alloc(NBH * 4);
  float*          P     = (float*)alloc((size_t)12 * BATCH * 64 * 4);
  float*          Qb    = (float*)alloc((size_t)BATCH * 64 * 4);

  k_convert<<<dim3((NW / 4 + 255) / 256), dim3(256), 0, stream>>>(lWih, Wih_b, (int)NW);
  k_convert<<<dim3((NW / 4 + 255) / 256), dim3(256), 0, stream>>>(lWhh, Whh_b, (int)NW);
  k_convert<<<dim3((NBH / 4 + 255) / 256), dim3(256), 0, stream>>>(x0, Xb, (int)NBH);
  k_wqp<<<dim3(256), dim3(256), 0, stream>>>(Wcurr, Wprev, Wqp_b);
  k_bias<<<dim3(16), dim3(256), 0, stream>>>(lbih, lbhh, biasS);
  {
    size_t zb = 2 * NBH * 2 + 2 * NBH * 2 + NBH * 4 + NBH * 4;  // Hb0,Hb1,C0,C1 contiguous
    int n16 = (int)(zb / 16);
    k_zero<<<dim3((n16 + 255) / 256), dim3(256), 0, stream>>>((uint4*)Hb0, n16);
  }
  k_p0<<<dim3(256), dim3(256), 0, stream>>>(P, bprev);

  // job builders (buffer parity: writer of step t uses parity (t+1)&1)
  auto jobL0 = [&](int u) {
    GJob j; j.X = Xb; j.H = Hb0 + (u & 1) * NBH;
    j.Wih = Wih_b; j.Whh = Whh_b; j.bias = biasS; j.C = C0;
    j.Hout = Hb0 + ((u + 1) & 1) * NBH; return j;
  };
  auto jobL1 = [&](int t) {
    GJob j; j.X = Hb0 + ((t + 1) & 1) * NBH; j.H = Hb1 + (t & 1) * NBH;
    j.Wih = Wih_b + 2048 * 512; j.Whh = Whh_b + 2048 * 512; j.bias = biasS + 2048; j.C = C1;
    j.Hout = Hb1 + ((t + 1) & 1) * NBH; return j;
  };
  auto h1of = [&](int t) { return (const unsigned short*)(Hb1 + ((t + 1) & 1) * NBH); };
  GJob dummy{}; CJob nocls{};

  // prologue: L0(step 0)
  k_gates2<0, false><<<dim3(512), dim3(256), 0, stream>>>(jobL0(0), dummy, nocls);

  for (int c = 0; c < 12; ++c) {
    const int t0 = 4 * c, t1 = t0 + 1, t2 = t0 + 2, t3 = t0 + 3;
    const int base = c * 29;
    CJob cls0{h1of(t0), Wc0, bc0, out, base};
    CJob cls1{h1of(t1), Wc1, bc1, out, base + 8};
    CJob cls2{h1of(t2), Wc2, bc2, out, base + 14};

    k_gates2<0, true><<<dim3(1024), dim3(256), 0, stream>>>(jobL1(t0), jobL0(t1), nocls);
    k_gates2<8, true><<<dim3(1056), dim3(256), 0, stream>>>(jobL1(t1), jobL0(t2), cls0);
    k_gates2<6, true><<<dim3(1056), dim3(256), 0, stream>>>(jobL1(t2), jobL0(t3), cls1);
    k_gates2<4, false><<<dim3(544), dim3(256), 0, stream>>>(jobL1(t3), dummy, cls2);

    k_qp<<<dim3(16, 8), dim3(256), 0, stream>>>(h1of(t3), Wqp_b, bcurr, bprev, Qb, P, c);
    switch (c) {
      case 0:  k_scores<0><<<dim3(256), dim3(256), 0, stream>>>(Qb, P, v, Wanc, banc, out, Xb); break;
      case 1:  k_scores<1><<<dim3(256), dim3(256), 0, stream>>>(Qb, P, v, Wanc, banc, out, Xb); break;
      case 2:  k_scores<2><<<dim3(256), dim3(256), 0, stream>>>(Qb, P, v, Wanc, banc, out, Xb); break;
      case 3:  k_scores<3><<<dim3(256), dim3(256), 0, stream>>>(Qb, P, v, Wanc, banc, out, Xb); break;
      case 4:  k_scores<4><<<dim3(256), dim3(256), 0, stream>>>(Qb, P, v, Wanc, banc, out, Xb); break;
      case 5:  k_scores<5><<<dim3(256), dim3(256), 0, stream>>>(Qb, P, v, Wanc, banc, out, Xb); break;
      case 6:  k_scores<6><<<dim3(256), dim3(256), 0, stream>>>(Qb, P, v, Wanc, banc, out, Xb); break;
      case 7:  k_scores<7><<<dim3(256), dim3(256), 0, stream>>>(Qb, P, v, Wanc, banc, out, Xb); break;
      case 8:  k_scores<8><<<dim3(256), dim3(256), 0, stream>>>(Qb, P, v, Wanc, banc, out, Xb); break;
      case 9:  k_scores<9><<<dim3(256), dim3(256), 0, stream>>>(Qb, P, v, Wanc, banc, out, Xb); break;
      case 10: k_scores<10><<<dim3(256), dim3(256), 0, stream>>>(Qb, P, v, Wanc, banc, out, Xb); break;
      default: k_scores<11><<<dim3(256), dim3(256), 0, stream>>>(Qb, P, v, Wanc, banc, out, Xb); break;
    }
    if (c < 11)
      k_gates2<0, false><<<dim3(512), dim3(256), 0, stream>>>(jobL0(t3 + 1), dummy, nocls);
  }
  (void)in_sizes; (void)n_in; (void)out_size; (void)ws_size;
}